// Round 9
// baseline (1154.564 us; speedup 1.0000x reference)
//
#include <hip/hip_runtime.h>
#include <hip/hip_bf16.h>
#include <hip/hip_fp16.h>
#include <hip/hip_cooperative_groups.h>

namespace cg = cooperative_groups;

typedef __attribute__((ext_vector_type(8))) short bf16x8;
typedef __attribute__((ext_vector_type(4))) float f32x4;
typedef unsigned int uint32;

#define F 128
#define HOPS 5
#define LDS_STRIDE 68
#define W1_STRIDE 136
#define W2_STRIDE 72
#define TB_STRIDE 72

__device__ __forceinline__ float b2f(__hip_bfloat16 h) { return __bfloat162float(h); }
__device__ __forceinline__ __hip_bfloat16 f2b(float f) { return __float2bfloat16(f); }

__device__ __forceinline__ float load_in(const void* p, size_t i, int isbf) {
    return isbf ? __bfloat162float(((const __hip_bfloat16*)p)[i]) : ((const float*)p)[i];
}

__device__ __forceinline__ float bflo(uint32 u) { union { uint32 i; float f; } v; v.i = u << 16; return v.f; }
__device__ __forceinline__ float bfhi(uint32 u) { union { uint32 i; float f; } v; v.i = u & 0xffff0000u; return v.f; }
__device__ __forceinline__ uint32 packbf2(float a, float b) {
    __hip_bfloat16 ha = f2b(a), hb = f2b(b);
    unsigned short ua = *(unsigned short*)&ha, ub = *(unsigned short*)&hb;
    return ((uint32)ub << 16) | ua;
}

// actual XCD id of the executing workgroup (uniform per wave)
__device__ __forceinline__ int xcd_id() {
    unsigned v;
    asm volatile("s_getreg_b32 %0, hwreg(HW_REG_XCC_ID)" : "=s"(v));
    return (int)(v & 7);
}

// leaky(x)*at summed == (0.6*at*ft)*fh + (0.4*at*|ft|)*|fh|  (leaky(x)=0.6x+0.4|x|)
__device__ __forceinline__ float edge_dot2(uint4 gv, const float* c1, const float* c2) {
    float acc = 0.f, acc2 = 0.f;
    uint32 us[4] = {gv.x, gv.y, gv.z, gv.w};
    #pragma unroll
    for (int k = 0; k < 4; ++k) {
        float f0 = bflo(us[k]), f1 = bfhi(us[k]);
        acc  = fmaf(c1[2 * k],     f0,        acc);
        acc2 = fmaf(c2[2 * k],     fabsf(f0), acc2);
        acc  = fmaf(c1[2 * k + 1], f1,        acc);
        acc2 = fmaf(c2[2 * k + 1], fabsf(f1), acc2);
    }
    return acc + acc2;
}

// ---------------- dtype detection ----------------
__global__ void detect_k(const uint32* __restrict__ w, int* flag) {
    __shared__ int cnt[256];
    int t = threadIdx.x;
    uint32 x = w[t * 97];
    int e_low = (x >> 7) & 0xFF;
    cnt[t] = (e_low >= 110 && e_low <= 135) ? 1 : 0;
    __syncthreads();
    for (int s = 128; s > 0; s >>= 1) {
        if (t < s) cnt[t] += cnt[t + s];
        __syncthreads();
    }
    if (t == 0) flag[0] = (cnt[0] >= 160) ? 1 : 0;
}

// ---------------- FUSED pre-stage: degree (atomic-latency-bound, blocks first)
// + ln1 + weight conversion run in its idle shadow ----------------
__global__ void fused_pre_k(const int* __restrict__ src, const int* __restrict__ dst,
                            int* in8, int* out1, uint32* __restrict__ pack, int E,
                            const void* __restrict__ feat, const void* __restrict__ ln1g,
                            const void* __restrict__ ln1b,
                            const void* __restrict__ w_head, const void* __restrict__ w_tail,
                            const void* __restrict__ w_ent, const void* __restrict__ ff_w1,
                            const void* __restrict__ ff_w2, const void* __restrict__ attn,
                            const void* __restrict__ ff_b1, const void* __restrict__ ff_b2,
                            const int* __restrict__ flag,
                            __hip_bfloat16* __restrict__ wblob, float* __restrict__ fblob,
                            __hip_bfloat16* __restrict__ x_bf,
                            int nbDeg, int nbLn, int N) {
    int bid = blockIdx.x;
    if (bid < nbDeg) {
        // ---- degree path: 8 edges/thread, returning atomics 8-deep in flight ----
        int base = bid * 2048 + threadIdx.x;
        int slice = xcd_id();
        int idx[8], d[8], s[8], r[8];
#pragma unroll
        for (int k = 0; k < 8; ++k) idx[k] = base + k * 256;
#pragma unroll
        for (int k = 0; k < 8; ++k)
            if (idx[k] < E) { d[k] = dst[idx[k]]; s[k] = src[idx[k]]; }
#pragma unroll
        for (int k = 0; k < 8; ++k)
            if (idx[k] < E) r[k] = atomicAdd(&in8[slice * N + d[k]], 1);
#pragma unroll
        for (int k = 0; k < 8; ++k)
            if (idx[k] < E) atomicAdd(&out1[s[k]], 1);
#pragma unroll
        for (int k = 0; k < 8; ++k)
            if (idx[k] < E) pack[idx[k]] = (uint32)r[k] | ((uint32)slice << 24);
        return;
    }
    if (bid < nbDeg + nbLn) {
        // ---- LayerNorm1 path ----
        int w = (bid - nbDeg) * 4 + (threadIdx.x >> 6);
        if (w >= N) return;
        int isbf = flag[0];
        int t = threadIdx.x & 63;
        float v0 = load_in(feat, (size_t)w * F + t, isbf);
        float v1 = load_in(feat, (size_t)w * F + t + 64, isbf);
        float s = v0 + v1, sq = v0 * v0 + v1 * v1;
        for (int m = 1; m < 64; m <<= 1) { s += __shfl_xor(s, m, 64); sq += __shfl_xor(sq, m, 64); }
        float mu = s * (1.0f / F);
        float var = fmaxf(sq * (1.0f / F) - mu * mu, 0.0f);
        float r = rsqrtf(var + 1e-5f);
        x_bf[(size_t)w * F + t]      = f2b((v0 - mu) * r * load_in(ln1g, t, isbf) + load_in(ln1b, t, isbf));
        x_bf[(size_t)w * F + t + 64] = f2b((v1 - mu) * r * load_in(ln1g, t + 64, isbf) + load_in(ln1b, t + 64, isbf));
        return;
    }
    // ---- weight/bias conversion path ----
    {
        int i = (bid - nbDeg - nbLn) * 256 + threadIdx.x;
        int isbf = flag[0];
        if (i < 180224) {
            const void* srcp; int j;
            if (i < 16384)       { srcp = w_head; j = i; }
            else if (i < 32768)  { srcp = w_tail; j = i - 16384; }
            else if (i < 49152)  { srcp = w_ent;  j = i - 32768; }
            else if (i < 114688) { srcp = ff_w1;  j = i - 49152; }
            else                 { srcp = ff_w2;  j = i - 114688; }
            wblob[i] = f2b(load_in(srcp, j, isbf));
        } else if (i < 180992) {
            int k = i - 180224;
            const void* srcp; int j;
            if (k < 128)      { srcp = attn;  j = k; }
            else if (k < 640) { srcp = ff_b1; j = k - 128; }
            else              { srcp = ff_b2; j = k - 640; }
            fblob[k] = load_in(srcp, j, isbf);
        }
    }
}

__global__ void scan1_k(const int* __restrict__ in8, int* partial, int* blk_sum, int N) {
    __shared__ int sh[256];
    int t = threadIdx.x;
    int i = blockIdx.x * 256 + t;
    int c = 0;
    if (i < N) {
#pragma unroll
        for (int s = 0; s < 8; ++s) c += in8[s * N + i];
    }
    sh[t] = c;
    __syncthreads();
    for (int o = 1; o < 256; o <<= 1) {
        int v = (t >= o) ? sh[t - o] : 0;
        __syncthreads();
        sh[t] += v;
        __syncthreads();
    }
    if (i < N) partial[i] = sh[t] - c;
    if (t == 255) blk_sum[blockIdx.x] = sh[255];
}

// fallback (nb > 256)
__global__ void scan2_k(const int* __restrict__ blk_sum, int* blk_off, int nb,
                        int* row_ptr, int N) {
    __shared__ int sh[256];
    int t = threadIdx.x;
    if (nb <= 256) {
        int v = (t < nb) ? blk_sum[t] : 0;
        sh[t] = v;
        __syncthreads();
        for (int o = 1; o < 256; o <<= 1) {
            int u = (t >= o) ? sh[t - o] : 0;
            __syncthreads();
            sh[t] += u;
            __syncthreads();
        }
        if (t < nb) blk_off[t] = sh[t] - v;
        if (t == 255) row_ptr[N] = sh[255];
    } else if (t == 0) {
        int run = 0;
        for (int b = 0; b < nb; ++b) { blk_off[b] = run; run += blk_sum[b]; }
        row_ptr[N] = run;
    }
}

__global__ void scan3_norms_k(const int* __restrict__ partial, const int* __restrict__ blk_off,
                              const int* __restrict__ in8, const int* __restrict__ out1,
                              int* row_ptr, int* soff, float* head_norm, float* tail_norm,
                              float* log_in, int N) {
    int i = blockIdx.x * 256 + threadIdx.x;
    if (i >= N) return;
    row_ptr[i] = partial[i] + blk_off[blockIdx.x];
    int run = 0;
#pragma unroll
    for (int s = 0; s < 8; ++s) { soff[s * N + i] = run; run += in8[s * N + i]; }
    int od = out1[i];
    float id = fmaxf((float)run, 1.0f);
    float odf = fmaxf((float)od, 1.0f);
    head_norm[i] = rsqrtf(odf);
    tail_norm[i] = sqrtf(id);
    log_in[i] = log1pf(id);
}

// fused scan2+scan3: each block re-scans blk_sum locally (nb <= 256)
__global__ void scan3f_k(const int* __restrict__ partial, const int* __restrict__ blk_sum,
                         int nb, const int* __restrict__ in8, const int* __restrict__ out1,
                         int* row_ptr, int* soff, float* head_norm, float* tail_norm,
                         float* log_in, int N) {
    __shared__ int bs[256];
    int t = threadIdx.x;
    bs[t] = (t < nb) ? blk_sum[t] : 0;
    __syncthreads();
    for (int o = 1; o < 256; o <<= 1) {
        int v = (t >= o) ? bs[t - o] : 0;
        __syncthreads();
        bs[t] += v;
        __syncthreads();
    }
    if (blockIdx.x == 0 && t == 0) row_ptr[N] = bs[nb - 1];
    int boff = (blockIdx.x == 0) ? 0 : bs[blockIdx.x - 1];
    int i = blockIdx.x * 256 + t;
    if (i >= N) return;
    row_ptr[i] = partial[i] + boff;
    int run = 0;
#pragma unroll
    for (int s = 0; s < 8; ++s) { soff[s * N + i] = run; run += in8[s * N + i]; }
    int od = out1[i];
    float id = fmaxf((float)run, 1.0f);
    float odf = fmaxf((float)od, 1.0f);
    head_norm[i] = rsqrtf(odf);
    tail_norm[i] = sqrtf(id);
    log_in[i] = log1pf(id);
}

// ---------------- FUSED mid-stage: atomic-free scatter (blocks first) + proj GEMM ----------------
__global__ void fused_mid_k(const int* __restrict__ src, const int* __restrict__ dst,
                            const int* __restrict__ row_ptr, const int* __restrict__ soff,
                            const uint32* __restrict__ pack, int* __restrict__ csr_src,
                            int E, int N, int nbSc, int Mb,
                            const __hip_bfloat16* __restrict__ X,
                            const __hip_bfloat16* __restrict__ Wall,
                            const float* __restrict__ head_norm,
                            __hip_bfloat16* __restrict__ fh,
                            __hip_bfloat16* __restrict__ ft,
                            uint32* __restrict__ fe_bf) {
    __shared__ __align__(16) char smem[2 * 64 * W1_STRIDE * 2];
    int bid = blockIdx.x;
    if (bid < nbSc) {
        // ---- scatter path: 8 edges/thread ----
        int base = bid * 2048 + threadIdx.x;
#pragma unroll
        for (int k = 0; k < 8; ++k) {
            int i = base + k * 256;
            if (i < E) {
                int d = dst[i];
                uint32 pk = pack[i];
                int s = (int)(pk >> 24);
                int r = (int)(pk & 0xFFFFFFu);
                csr_src[row_ptr[d] + soff[s * N + d] + r] = src[i];
            }
        }
        return;
    }
    // ---- projection GEMM path ----
    int pb = bid - nbSc;
    int g = pb / Mb;
    int bm = (pb - g * Mb) * 64;
    __hip_bfloat16* lx = (__hip_bfloat16*)smem;
    __hip_bfloat16* lw = (__hip_bfloat16*)(smem + 64 * W1_STRIDE * 2);
    float* eps = (float*)smem;
    int tid = threadIdx.x;
    int wv = tid >> 6, lane = tid & 63;
    int lr = lane & 15, quad = lane >> 4;
    int wsel = g >> 1;
    int wcb = (g & 1) * 64;
    {
        const __hip_bfloat16* xs = X + (size_t)bm * F;
        size_t maxe = (size_t)N * F;
#pragma unroll
        for (int i = 0; i < 4; ++i) {
            int idx = i * 2048 + tid * 8;
            int n = idx >> 7, k = idx & 127;
            size_t gi = (size_t)bm * F + idx;
            uint4 v = (gi + 8 <= maxe) ? *(const uint4*)(xs + idx)
                                       : *(const uint4*)(X + maxe - 8);
            *(uint4*)&lx[n * W1_STRIDE + k] = v;
        }
        const __hip_bfloat16* ws = Wall + ((size_t)wsel * F + wcb) * F;
#pragma unroll
        for (int i = 0; i < 4; ++i) {
            int idx = i * 2048 + tid * 8;
            int n = idx >> 7, k = idx & 127;
            *(uint4*)&lw[n * W1_STRIDE + k] = *(const uint4*)(ws + idx);
        }
    }
    __syncthreads();
    f32x4 acc[4] = {{0,0,0,0},{0,0,0,0},{0,0,0,0},{0,0,0,0}};
#pragma unroll
    for (int ks = 0; ks < 4; ++ks) {
        bf16x8 a = *reinterpret_cast<const bf16x8*>(&lx[(wv * 16 + lr) * W1_STRIDE + ks * 32 + quad * 8]);
#pragma unroll
        for (int j = 0; j < 4; ++j) {
            bf16x8 bb = *reinterpret_cast<const bf16x8*>(&lw[(j * 16 + lr) * W1_STRIDE + ks * 32 + quad * 8]);
            acc[j] = __builtin_amdgcn_mfma_f32_16x16x32_bf16(a, bb, acc[j], 0, 0, 0);
        }
    }
    __syncthreads();
    int rl = wv * 16 + quad * 4;
#pragma unroll
    for (int j = 0; j < 4; ++j)
#pragma unroll
        for (int r = 0; r < 4; ++r)
            eps[(rl + r) * LDS_STRIDE + j * 16 + lr] = acc[j][r];
    __syncthreads();
    int tr = tid >> 4, tc = (tid & 15) * 4;
#pragma unroll
    for (int p = 0; p < 4; ++p) {
        int row_l = p * 16 + tr;
        int grow = bm + row_l;
        if (grow >= N) continue;
        float4 v = *(const float4*)&eps[row_l * LDS_STRIDE + tc];
        float hn = head_norm[grow];
        v.x *= hn; v.y *= hn; v.z *= hn; v.w *= hn;
        size_t idx = (size_t)grow * F + wcb + tc;
        uint2 u; u.x = packbf2(v.x, v.y); u.y = packbf2(v.z, v.w);
        __hip_bfloat16* dstp = (wsel == 0) ? fh : (wsel == 1) ? ft : (__hip_bfloat16*)fe_bf;
        *(uint2*)&dstp[idx] = u;
    }
}

// ---------------- FUSED edge attention + softmax + hop0 (R7 two-pass, proven) ----------------
// pass1: logits (16 lanes/edge), per-head max. pass2: lane t owns (edge t&7,
// head t>>3) -> ONE exp per lane (64 unique (edge,head) per batch), coalesced
// e_h load/store, __shfl distributes ex to the fe-gather accumulation.
__global__ void attn_hop0_k(const int* __restrict__ csr_src, const int* __restrict__ row_ptr,
                            const uint32* __restrict__ fh2, const uint32* __restrict__ ft2,
                            const float* __restrict__ attn_f, const float* __restrict__ log_in,
                            const float* __restrict__ tail_norm, const float* __restrict__ head_norm,
                            const uint32* __restrict__ fe_bf,
                            __half* __restrict__ e_h, float* __restrict__ inv_arr,
                            uint32* __restrict__ out_bf, int N) {
    int w = blockIdx.x * (blockDim.x >> 6) + (threadIdx.x >> 6);
    if (w >= N) return;
    int t = threadIdx.x & 63;
    int g = t >> 4, j = t & 15;
    int b = row_ptr[w], e = row_ptr[w + 1];
    // ---- pass1: logits ----
    uint4 fr = ((const uint4*)ft2)[(size_t)w * 16 + j];
    float ftf[8] = {bflo(fr.x), bfhi(fr.x), bflo(fr.y), bfhi(fr.y),
                    bflo(fr.z), bfhi(fr.z), bflo(fr.w), bfhi(fr.w)};
    float c1[8], c2[8];
#pragma unroll
    for (int k = 0; k < 8; ++k) {
        float at = attn_f[8 * j + k];
        c1[k] = 0.6f * at * ftf[k];
        c2[k] = 0.4f * at * fabsf(ftf[k]);
    }
    float scale = log_in[w] * (1.0f / 16.0f);
    float m = -1e30f;
    for (int p0 = b; p0 < e; p0 += 8) {
        int pa = p0 + g, pb = p0 + 4 + g;
        bool oka = pa < e, okb = pb < e;
        int sa = csr_src[oka ? pa : b];
        int sb = csr_src[okb ? pb : b];
        uint4 ga = ((const uint4*)fh2)[(size_t)sa * 16 + j];
        uint4 gb = ((const uint4*)fh2)[(size_t)sb * 16 + j];
        float ra = edge_dot2(ga, c1, c2);
        float rb = edge_dot2(gb, c1, c2);
        ra += __shfl_xor(ra, 1, 64);
        rb += __shfl_xor(rb, 1, 64);
        float la = ra * scale, lb = rb * scale;
        if (oka) { if (!(j & 1)) e_h[(size_t)pa * 8 + (j >> 1)] = __float2half(la); m = fmaxf(m, la); }
        if (okb) { if (!(j & 1)) e_h[(size_t)pb * 8 + (j >> 1)] = __float2half(lb); m = fmaxf(m, lb); }
    }
    m = fmaxf(m, __shfl_xor(m, 16, 64));
    m = fmaxf(m, __shfl_xor(m, 32, 64));
    // ---- pass2: lane t owns (edge t&7, head t>>3); one exp/lane/batch ----
    int h = t >> 3;
    int il = t & 7;
    float mh = __shfl(m, h * 2, 64);
    float sum = 0.f, a0 = 0.f, a1 = 0.f;
    for (int p = b; p < e; p += 8) {
        int qo = p + il;
        bool okm = qo < e;
        int qm = okm ? qo : b;
        float lg = __half2float(e_h[(size_t)qm * 8 + h]);
        float exm = okm ? __expf(lg - mh) : 0.f;
        if (okm) e_h[(size_t)qm * 8 + h] = __float2half(exm);
        int srcs[8];
#pragma unroll
        for (int i = 0; i < 8; ++i) {
            int qi = p + i;
            srcs[i] = csr_src[qi < e ? qi : b];
        }
        uint32 rows[8];
#pragma unroll
        for (int i = 0; i < 8; ++i) rows[i] = fe_bf[(size_t)srcs[i] * 64 + t];
#pragma unroll
        for (int i = 0; i < 8; ++i) {
            float exi = __shfl(exm, (t & 56) | i, 64);
            sum += exi;
            a0 = fmaf(bflo(rows[i]), exi, a0);
            a1 = fmaf(bfhi(rows[i]), exi, a1);
        }
    }
    float inv = 1.0f / fmaxf(sum, 1e-30f);
    if ((t & 7) == 0) inv_arr[(size_t)w * 8 + h] = inv;
    float tl = tail_norm[w] * 0.9f * inv;
    uint32 fe_l = fe_bf[(size_t)w * 64 + t];
    float r0 = tl * a0 + 0.1f * bflo(fe_l);
    float r1 = tl * a1 + 0.1f * bfhi(fe_l);
    float hn = head_norm[w];
    out_bf[(size_t)w * 64 + t] = packbf2(r0 * hn, r1 * hn);
}

// ---------------- shared hop body (used by both coop and fallback kernels) ----------------
__device__ __forceinline__ void hop_body(int w, const uint32* gsrc2, const __half* e_h,
                                         const float* inv_arr, const int* csr_src,
                                         const int* row_ptr, const float* tail_norm,
                                         const float* head_norm, const uint32* fe_bf,
                                         const void* feat, const void* ln2g,
                                         const void* ln2b, const int* flag,
                                         uint32* out_bf, float* out_f32, int last) {
    int l = threadIdx.x & 31;                      // features [4l, 4l+4)
    int h = l >> 2;
    int b = row_ptr[w], e = row_ptr[w + 1];
    float inv = inv_arr[(size_t)w * 8 + h];
    float a0 = 0.f, a1 = 0.f, a2 = 0.f, a3 = 0.f;
    int p = b;
    for (; p + 8 <= e; p += 8) {
        int s[8]; float av[8]; uint2 gg[8];
#pragma unroll
        for (int i = 0; i < 8; ++i) s[i] = csr_src[p + i];
#pragma unroll
        for (int i = 0; i < 8; ++i) av[i] = __half2float(e_h[(size_t)(p + i) * 8 + h]);
#pragma unroll
        for (int i = 0; i < 8; ++i) gg[i] = ((const uint2*)gsrc2)[(size_t)s[i] * 32 + l];
#pragma unroll
        for (int i = 0; i < 8; ++i) {
            a0 += bflo(gg[i].x) * av[i]; a1 += bfhi(gg[i].x) * av[i];
            a2 += bflo(gg[i].y) * av[i]; a3 += bfhi(gg[i].y) * av[i];
        }
    }
    if (p < e) {
        int s[8]; float av[8]; uint2 gg[8];
#pragma unroll
        for (int i = 0; i < 8; ++i) {
            int q = p + i;
            bool ok = q < e;
            int q2 = ok ? q : b;
            s[i] = csr_src[q2];
            av[i] = ok ? __half2float(e_h[(size_t)q * 8 + h]) : 0.f;
        }
#pragma unroll
        for (int i = 0; i < 8; ++i) gg[i] = ((const uint2*)gsrc2)[(size_t)s[i] * 32 + l];
#pragma unroll
        for (int i = 0; i < 8; ++i) {
            a0 += bflo(gg[i].x) * av[i]; a1 += bfhi(gg[i].x) * av[i];
            a2 += bflo(gg[i].y) * av[i]; a3 += bfhi(gg[i].y) * av[i];
        }
    }
    float tl = tail_norm[w] * 0.9f * inv;
    uint2 feu = ((const uint2*)fe_bf)[(size_t)w * 32 + l];
    float r0 = tl * a0 + 0.1f * bflo(feu.x);
    float r1 = tl * a1 + 0.1f * bfhi(feu.x);
    float r2 = tl * a2 + 0.1f * bflo(feu.y);
    float r3 = tl * a3 + 0.1f * bfhi(feu.y);
    if (last) {
        int isbf = flag[0];
        float4 o;
        if (isbf) {
            uint2 fu = ((const uint2*)feat)[(size_t)w * 32 + l];
            o.x = r0 + bflo(fu.x); o.y = r1 + bfhi(fu.x);
            o.z = r2 + bflo(fu.y); o.w = r3 + bfhi(fu.y);
        } else {
            float4 fv = ((const float4*)feat)[(size_t)w * 32 + l];
            o.x = r0 + fv.x; o.y = r1 + fv.y; o.z = r2 + fv.z; o.w = r3 + fv.w;
        }
        ((float4*)out_f32)[(size_t)w * 32 + l] = o;
        // fused LN2 over the 32-lane half-wave (128 features)
        float s2 = o.x + o.y + o.z + o.w;
        float sq = o.x * o.x + o.y * o.y + o.z * o.z + o.w * o.w;
#pragma unroll
        for (int mm = 1; mm < 32; mm <<= 1) {
            s2 += __shfl_xor(s2, mm, 64);
            sq += __shfl_xor(sq, mm, 64);
        }
        float mu = s2 * (1.0f / F);
        float var = fmaxf(sq * (1.0f / F) - mu * mu, 0.0f);
        float rr = rsqrtf(var + 1e-5f);
        float g0 = load_in(ln2g, 4 * l + 0, isbf), g1 = load_in(ln2g, 4 * l + 1, isbf);
        float g2 = load_in(ln2g, 4 * l + 2, isbf), g3 = load_in(ln2g, 4 * l + 3, isbf);
        float b0 = load_in(ln2b, 4 * l + 0, isbf), b1 = load_in(ln2b, 4 * l + 1, isbf);
        float b2 = load_in(ln2b, 4 * l + 2, isbf), b3 = load_in(ln2b, 4 * l + 3, isbf);
        uint2 u;
        u.x = packbf2((o.x - mu) * rr * g0 + b0, (o.y - mu) * rr * g1 + b1);
        u.y = packbf2((o.z - mu) * rr * g2 + b2, (o.w - mu) * rr * g3 + b3);
        ((uint2*)out_bf)[(size_t)w * 32 + l] = u;
    } else {
        float hn = head_norm[w];
        uint2 u;
        u.x = packbf2(r0 * hn, r1 * hn);
        u.y = packbf2(r2 * hn, r3 * hn);
        ((uint2*)out_bf)[(size_t)w * 32 + l] = u;
    }
}

// ---------------- COOPERATIVE merged hops 1..4: one launch, grid.sync between hops.
// Fixed block->node mapping gives cross-hop L2 reuse of csr_src/e_h rows. ----------------
__global__ __launch_bounds__(256, 4)
void hop_coop_k(uint32* hA, uint32* hB, const __half* __restrict__ e_h,
                const float* __restrict__ inv_arr,
                const int* __restrict__ csr_src, const int* __restrict__ row_ptr,
                const float* __restrict__ tail_norm, const float* __restrict__ head_norm,
                const uint32* __restrict__ fe_bf, const void* __restrict__ feat,
                const void* __restrict__ ln2g, const void* __restrict__ ln2b,
                const int* __restrict__ flag, float* __restrict__ rst,
                int N, int nGroups) {
    cg::grid_group grid = cg::this_grid();
    for (int hop = 1; hop < HOPS; ++hop) {
        int last = (hop == HOPS - 1);
        const uint32* gsrc = (hop & 1) ? hA : hB;   // h1:A->B h2:B->A h3:A->B h4:B->A(=y_bf)
        uint32* dstp       = (hop & 1) ? hB : hA;
        for (int grp = blockIdx.x; grp < nGroups; grp += gridDim.x) {
            int w = grp * 8 + (threadIdx.x >> 5);
            if (w < N)
                hop_body(w, gsrc, e_h, inv_arr, csr_src, row_ptr, tail_norm, head_norm,
                         fe_bf, feat, ln2g, ln2b, flag, dstp, rst, last);
        }
        if (!last) {
            __threadfence();
            grid.sync();
        }
    }
}

// ---------------- fallback: single-hop kernel (used if coop launch unavailable) ----------------
__global__ void hop_k(const uint32* __restrict__ gsrc2, const __half* __restrict__ e_h,
                      const float* __restrict__ inv_arr,
                      const int* __restrict__ csr_src, const int* __restrict__ row_ptr,
                      const float* __restrict__ tail_norm, const float* __restrict__ head_norm,
                      const uint32* __restrict__ fe_bf, const void* __restrict__ feat,
                      const void* __restrict__ ln2g, const void* __restrict__ ln2b,
                      const int* __restrict__ flag,
                      uint32* __restrict__ out_bf, float* __restrict__ out_f32,
                      int last, int N) {
    int w = blockIdx.x * 8 + (threadIdx.x >> 5);
    if (w >= N) return;
    hop_body(w, gsrc2, e_h, inv_arr, csr_src, row_ptr, tail_norm, head_norm,
             fe_bf, feat, ln2g, ln2b, flag, out_bf, out_f32, last);
}

// ---------------- FUSED FFN v3 (LDS-staged weights) ----------------
__global__ __launch_bounds__(256, 2)
void ffn_fused_k(const __hip_bfloat16* __restrict__ Y, const __hip_bfloat16* __restrict__ W1,
                 const __hip_bfloat16* __restrict__ W2, const float* __restrict__ b1f,
                 const float* __restrict__ b2f, const float* __restrict__ rst,
                 const int* __restrict__ flag, void* __restrict__ out, int N) {
    __shared__ __align__(16) char smem[45056];
    __hip_bfloat16* lw1 = (__hip_bfloat16*)smem;
    __hip_bfloat16* lw2 = (__hip_bfloat16*)(smem + 17408);
    __hip_bfloat16* tb  = (__hip_bfloat16*)(smem + 35840);
    float* eps = (float*)smem;
    int tid = threadIdx.x;
    int wv = tid >> 6, lane = tid & 63;
    int lr = lane & 15, quad = lane >> 4;
    int bm = blockIdx.x * 64;
    int row_a = bm + wv * 16 + lr;
    if (row_a >= N) row_a = N - 1;
    bf16x8 ay[4];
    {
        const __hip_bfloat16* yr = Y + (size_t)row_a * F + quad * 8;
#pragma unroll
        for (int ks = 0; ks < 4; ++ks) ay[ks] = *reinterpret_cast<const bf16x8*>(yr + ks * 32);
    }
    f32x4 o[8];
#pragma unroll
    for (int j = 0; j < 8; ++j) o[j] = (f32x4){0,0,0,0};
    __hip_bfloat16* tbuf = tb + wv * (16 * TB_STRIDE);
    for (int c = 0; c < 8; ++c) {
        int nb0 = c * 64;
        __syncthreads();
        {
            const __hip_bfloat16* s1 = W1 + (size_t)nb0 * F;
#pragma unroll
            for (int i = 0; i < 4; ++i) {
                int idx = i * 2048 + tid * 8;
                int n = idx >> 7, k = idx & 127;
                *(uint4*)&lw1[n * W1_STRIDE + k] = *(const uint4*)(s1 + idx);
            }
#pragma unroll
            for (int i = 0; i < 4; ++i) {
                int idx = i * 2048 + tid * 8;
                int r = idx >> 6, k2 = idx & 63;
                *(uint4*)&lw2[r * W2_STRIDE + k2] = *(const uint4*)(W2 + (size_t)r * 512 + nb0 + k2);
            }
        }
        __syncthreads();
        f32x4 t[4] = {{0,0,0,0},{0,0,0,0},{0,0,0,0},{0,0,0,0}};
#pragma unroll
        for (int ks = 0; ks < 4; ++ks) {
#pragma unroll
            for (int j = 0; j < 4; ++j) {
                bf16x8 bb = *reinterpret_cast<const bf16x8*>(&lw1[(j * 16 + lr) * W1_STRIDE + ks * 32 + quad * 8]);
                t[j] = __builtin_amdgcn_mfma_f32_16x16x32_bf16(ay[ks], bb, t[j], 0, 0, 0);
            }
        }
#pragma unroll
        for (int j = 0; j < 4; ++j) {
            float bias = b1f[nb0 + 16 * j + lr];
#pragma unroll
            for (int r = 0; r < 4; ++r) {
                float v = fmaxf(t[j][r] + bias, 0.f);
                tbuf[(quad * 4 + r) * TB_STRIDE + j * 16 + lr] = f2b(v);
            }
        }
#pragma unroll
        for (int ks2 = 0; ks2 < 2; ++ks2) {
            bf16x8 at = *reinterpret_cast<const bf16x8*>(&tbuf[lr * TB_STRIDE + ks2 * 32 + quad * 8]);
#pragma unroll
            for (int j2 = 0; j2 < 8; ++j2) {
                bf16x8 bb = *reinterpret_cast<const bf16x8*>(&lw2[(j2 * 16 + lr) * W2_STRIDE + ks2 * 32 + quad * 8]);
                o[j2] = __builtin_amdgcn_mfma_f32_16x16x32_bf16(at, bb, o[j2], 0, 0, 0);
            }
        }
    }
    __syncthreads();
    int rl = wv * 16 + quad * 4;
#pragma unroll
    for (int j = 0; j < 8; ++j)
#pragma unroll
        for (int r = 0; r < 4; ++r)
            eps[(rl + r) * 132 + j * 16 + lr] = o[j][r];
    __syncthreads();
    int isbf = flag[0];
#pragma unroll
    for (int p = 0; p < 8; ++p) {
        int idx = p * 1024 + tid * 4;
        int row_l = idx >> 7, col = idx & 127;
        int grow = bm + row_l;
        if (grow >= N) continue;
        float4 v = *(const float4*)&eps[row_l * 132 + col];
        float4 bias = *(const float4*)&b2f[col];
        float4 rv = *(const float4*)&rst[(size_t)grow * F + col];
        v.x += bias.x + rv.x; v.y += bias.y + rv.y;
        v.z += bias.z + rv.z; v.w += bias.w + rv.w;
        size_t gidx = (size_t)grow * F + col;
        if (isbf) {
            uint2 u; u.x = packbf2(v.x, v.y); u.y = packbf2(v.z, v.w);
            *(uint2*)&((__hip_bfloat16*)out)[gidx] = u;
        } else {
            *(float4*)&((float*)out)[gidx] = v;
        }
    }
}

extern "C" void kernel_launch(void* const* d_in, const int* in_sizes, int n_in,
                              void* d_out, int out_size, void* d_ws, size_t ws_size,
                              hipStream_t stream) {
    if (n_in < 15) return;
    const void* feat = d_in[0];
    const int* src = (const int*)d_in[1];
    const int* dst = (const int*)d_in[2];
    const void* w_head = d_in[3];
    const void* w_tail = d_in[4];
    const void* w_ent  = d_in[5];
    const void* attn   = d_in[6];
    const void* ln1_g  = d_in[7];
    const void* ln1_b  = d_in[8];
    const void* ln2_g  = d_in[9];
    const void* ln2_b  = d_in[10];
    const void* ff_w1  = d_in[11];
    const void* ff_b1  = d_in[12];
    const void* ff_w2  = d_in[13];
    const void* ff_b2  = d_in[14];

    const int N = in_sizes[0] / F;
    const int E = in_sizes[1];
    (void)out_size;

    char* base = (char*)d_ws;
    size_t off = 0;
    auto alloc = [&](size_t bytes) -> void* {
        void* r = base + off;
        off += (bytes + 255) & ~(size_t)255;
        return r;
    };
    int* zr        = (int*)alloc((size_t)9 * N * 4);   // in8 | out1 (zeroed)
    int* in8 = zr, * out1 = zr + 8 * N;
    int* soff      = (int*)alloc((size_t)8 * N * 4);
    int* row_ptr   = (int*)alloc((size_t)(N + 1) * 4);
    int* partial   = (int*)alloc((size_t)N * 4);
    int* blk_sum   = (int*)alloc((size_t)1024 * 4);
    int* blk_off   = (int*)alloc((size_t)1024 * 4);
    int* flag      = (int*)alloc(256);
    float* head_norm = (float*)alloc((size_t)N * 4);
    float* tail_norm = (float*)alloc((size_t)N * 4);
    float* log_in    = (float*)alloc((size_t)N * 4);
    float* inv_arr   = (float*)alloc((size_t)N * 8 * 4);
    int* csr_src   = (int*)alloc((size_t)E * 4);
    uint32* pack   = (uint32*)alloc((size_t)E * 4);
    __hip_bfloat16* wh_bf = (__hip_bfloat16*)alloc((size_t)F * F * 2);   // blob start
    __hip_bfloat16* wt_bf = (__hip_bfloat16*)alloc((size_t)F * F * 2);
    __hip_bfloat16* we_bf = (__hip_bfloat16*)alloc((size_t)F * F * 2);
    __hip_bfloat16* w1_bf = (__hip_bfloat16*)alloc((size_t)512 * F * 2);
    __hip_bfloat16* w2_bf = (__hip_bfloat16*)alloc((size_t)F * 512 * 2);
    float* attn_f    = (float*)alloc((size_t)F * 4);
    float* b1f       = (float*)alloc((size_t)512 * 4);
    float* b2f_      = (float*)alloc((size_t)F * 4);
    __hip_bfloat16* x_bf = (__hip_bfloat16*)alloc((size_t)N * F * 2);
    __hip_bfloat16* fh   = (__hip_bfloat16*)alloc((size_t)N * F * 2);
    __hip_bfloat16* ftb  = (__hip_bfloat16*)alloc((size_t)N * F * 2);
    uint32* fe_bf = (uint32*)alloc((size_t)N * F * 2);
    uint32* hA_bf = (uint32*)alloc((size_t)N * F * 2);
    uint32* hB_bf = (uint32*)alloc((size_t)N * F * 2);
    float* rst = (float*)alloc((size_t)N * F * 4);
    __hip_bfloat16* y_bf = (__hip_bfloat16*)hA_bf;
    __half* e_h = (__half*)x_bf;   // x_bf is dead after fused_mid (proj); E*8*2 <= N*F*2
    (void)wt_bf; (void)we_bf;
    if (off > ws_size) return;

    const int Mb = (N + 63) / 64;
    const int nodeBlocks = (N + 3) / 4;
    const int hopBlocks = (N + 7) / 8;
    const int nb = (N + 255) / 256;
    const int nbDeg = (E + 2047) / 2048;
    const int nbLn  = (N + 3) / 4;
    const int nbCvt = (180992 + 255) / 256;

    detect_k<<<1, 256, 0, stream>>>((const uint32*)feat, flag);
    hipMemsetAsync(zr, 0, (size_t)9 * N * 4, stream);

    fused_pre_k<<<nbDeg + nbLn + nbCvt, 256, 0, stream>>>(
        src, dst, in8, out1, pack, E,
        feat, ln1_g, ln1_b,
        w_head, w_tail, w_ent, ff_w1, ff_w2, attn, ff_b1, ff_b2,
        flag, wh_bf, attn_f, x_bf, nbDeg, nbLn, N);

    scan1_k<<<nb, 256, 0, stream>>>(in8, partial, blk_sum, N);
    if (nb <= 256) {
        scan3f_k<<<nb, 256, 0, stream>>>(partial, blk_sum, nb, in8, out1,
                                         row_ptr, soff, head_norm, tail_norm, log_in, N);
    } else {
        scan2_k<<<1, 256, 0, stream>>>(blk_sum, blk_off, nb, row_ptr, N);
        scan3_norms_k<<<nb, 256, 0, stream>>>(partial, blk_off, in8, out1,
                                              row_ptr, soff, head_norm, tail_norm, log_in, N);
    }

    const int nbSc = (E + 2047) / 2048;
    fused_mid_k<<<nbSc + Mb * 6, 256, 0, stream>>>(
        src, dst, row_ptr, soff, pack, csr_src, E, N, nbSc, Mb,
        x_bf, wh_bf, head_norm, fh, ftb, fe_bf);

    // fused attention softmax + hop0 (writes hA_bf)
    attn_hop0_k<<<nodeBlocks, 256, 0, stream>>>(csr_src, row_ptr, (const uint32*)fh,
                                                (const uint32*)ftb, attn_f, log_in,
                                                tail_norm, head_norm, fe_bf,
                                                e_h, inv_arr, hA_bf, N);

    // hops 1..4: single cooperative launch (grid.sync between hops);
    // fallback to 4 separate launches if cooperative launch is rejected.
    {
        const int nGroups = (N + 7) / 8;
        uint32* hAp = hA_bf; uint32* hBp = hB_bf;
        const __half* ehp = e_h; const float* invp = inv_arr;
        const int* csrp = csr_src; const int* rpp = row_ptr;
        const float* tnp = tail_norm; const float* hnp = head_norm;
        const uint32* fep = fe_bf; const void* fp = feat;
        const void* g2p = ln2_g; const void* b2p = ln2_b;
        const int* flp = flag; float* rstp = rst;
        int N_ = N, nG = nGroups;
        void* args[] = {&hAp, &hBp, &ehp, &invp, &csrp, &rpp, &tnp, &hnp,
                        &fep, &fp, &g2p, &b2p, &flp, &rstp, &N_, &nG};
        hipError_t ce = hipLaunchCooperativeKernel(
            reinterpret_cast<void*>(hop_coop_k), dim3(1024), dim3(256), args, 0, stream);
        if (ce != hipSuccess) {
            const uint32* gsrc = hA_bf;
            uint32* bufs[2] = {hA_bf, hB_bf};
            for (int hop = 1; hop < HOPS; ++hop) {
                int last = (hop == HOPS - 1);
                uint32* dst_bf = last ? (uint32*)y_bf : bufs[hop & 1];
                hop_k<<<hopBlocks, 256, 0, stream>>>(gsrc, e_h, inv_arr, csr_src, row_ptr,
                                                     tail_norm, head_norm, fe_bf, feat,
                                                     ln2_g, ln2_b, flag, dst_bf, rst, last, N);
                if (!last) gsrc = dst_bf;
            }
        }
    }

    ffn_fused_k<<<Mb, 256, 0, stream>>>(y_bf, w1_bf, w2_bf, b1f, b2f_, rst, flag, d_out, N);
}

// Round 10
// 418.542 us; speedup vs baseline: 2.7585x; 2.7585x over previous
//
#include <hip/hip_runtime.h>
#include <hip/hip_bf16.h>
#include <hip/hip_fp16.h>

typedef __attribute__((ext_vector_type(8))) short bf16x8;
typedef __attribute__((ext_vector_type(4))) float f32x4;
typedef unsigned int uint32;

#define F 128
#define HOPS 5
#define LDS_STRIDE 68
#define W1_STRIDE 136
#define W2_STRIDE 72
#define TB_STRIDE 72

__device__ __forceinline__ float b2f(__hip_bfloat16 h) { return __bfloat162float(h); }
__device__ __forceinline__ __hip_bfloat16 f2b(float f) { return __float2bfloat16(f); }

__device__ __forceinline__ float load_in(const void* p, size_t i, int isbf) {
    return isbf ? __bfloat162float(((const __hip_bfloat16*)p)[i]) : ((const float*)p)[i];
}

__device__ __forceinline__ float bflo(uint32 u) { union { uint32 i; float f; } v; v.i = u << 16; return v.f; }
__device__ __forceinline__ float bfhi(uint32 u) { union { uint32 i; float f; } v; v.i = u & 0xffff0000u; return v.f; }
__device__ __forceinline__ uint32 packbf2(float a, float b) {
    __hip_bfloat16 ha = f2b(a), hb = f2b(b);
    unsigned short ua = *(unsigned short*)&ha, ub = *(unsigned short*)&hb;
    return ((uint32)ub << 16) | ua;
}

// actual XCD id of the executing workgroup (uniform per wave)
__device__ __forceinline__ int xcd_id() {
    unsigned v;
    asm volatile("s_getreg_b32 %0, hwreg(HW_REG_XCC_ID)" : "=s"(v));
    return (int)(v & 7);
}

// leaky(x)*at summed == (0.6*at*ft)*fh + (0.4*at*|ft|)*|fh|  (leaky(x)=0.6x+0.4|x|)
__device__ __forceinline__ float edge_dot2(uint4 gv, const float* c1, const float* c2) {
    float acc = 0.f, acc2 = 0.f;
    uint32 us[4] = {gv.x, gv.y, gv.z, gv.w};
    #pragma unroll
    for (int k = 0; k < 4; ++k) {
        float f0 = bflo(us[k]), f1 = bfhi(us[k]);
        acc  = fmaf(c1[2 * k],     f0,        acc);
        acc2 = fmaf(c2[2 * k],     fabsf(f0), acc2);
        acc  = fmaf(c1[2 * k + 1], f1,        acc);
        acc2 = fmaf(c2[2 * k + 1], fabsf(f1), acc2);
    }
    return acc + acc2;
}

// ---------------- dtype detection ----------------
__global__ void detect_k(const uint32* __restrict__ w, int* flag) {
    __shared__ int cnt[256];
    int t = threadIdx.x;
    uint32 x = w[t * 97];
    int e_low = (x >> 7) & 0xFF;
    cnt[t] = (e_low >= 110 && e_low <= 135) ? 1 : 0;
    __syncthreads();
    for (int s = 128; s > 0; s >>= 1) {
        if (t < s) cnt[t] += cnt[t + s];
        __syncthreads();
    }
    if (t == 0) flag[0] = (cnt[0] >= 160) ? 1 : 0;
}

// ---------------- FUSED pre-stage: degree (atomic-latency-bound, blocks first)
// + ln1 + weight conversion run in its idle shadow ----------------
__global__ void fused_pre_k(const int* __restrict__ src, const int* __restrict__ dst,
                            int* in8, int* out1, uint32* __restrict__ pack, int E,
                            const void* __restrict__ feat, const void* __restrict__ ln1g,
                            const void* __restrict__ ln1b,
                            const void* __restrict__ w_head, const void* __restrict__ w_tail,
                            const void* __restrict__ w_ent, const void* __restrict__ ff_w1,
                            const void* __restrict__ ff_w2, const void* __restrict__ attn,
                            const void* __restrict__ ff_b1, const void* __restrict__ ff_b2,
                            const int* __restrict__ flag,
                            __hip_bfloat16* __restrict__ wblob, float* __restrict__ fblob,
                            __hip_bfloat16* __restrict__ x_bf,
                            int nbDeg, int nbLn, int N) {
    int bid = blockIdx.x;
    if (bid < nbDeg) {
        // ---- degree path: 8 edges/thread, returning atomics 8-deep in flight ----
        int base = bid * 2048 + threadIdx.x;
        int slice = xcd_id();
        int idx[8], d[8], s[8], r[8];
#pragma unroll
        for (int k = 0; k < 8; ++k) idx[k] = base + k * 256;
#pragma unroll
        for (int k = 0; k < 8; ++k)
            if (idx[k] < E) { d[k] = dst[idx[k]]; s[k] = src[idx[k]]; }
#pragma unroll
        for (int k = 0; k < 8; ++k)
            if (idx[k] < E) r[k] = atomicAdd(&in8[slice * N + d[k]], 1);
#pragma unroll
        for (int k = 0; k < 8; ++k)
            if (idx[k] < E) atomicAdd(&out1[s[k]], 1);
#pragma unroll
        for (int k = 0; k < 8; ++k)
            if (idx[k] < E) pack[idx[k]] = (uint32)r[k] | ((uint32)slice << 24);
        return;
    }
    if (bid < nbDeg + nbLn) {
        // ---- LayerNorm1 path ----
        int w = (bid - nbDeg) * 4 + (threadIdx.x >> 6);
        if (w >= N) return;
        int isbf = flag[0];
        int t = threadIdx.x & 63;
        float v0 = load_in(feat, (size_t)w * F + t, isbf);
        float v1 = load_in(feat, (size_t)w * F + t + 64, isbf);
        float s = v0 + v1, sq = v0 * v0 + v1 * v1;
        for (int m = 1; m < 64; m <<= 1) { s += __shfl_xor(s, m, 64); sq += __shfl_xor(sq, m, 64); }
        float mu = s * (1.0f / F);
        float var = fmaxf(sq * (1.0f / F) - mu * mu, 0.0f);
        float r = rsqrtf(var + 1e-5f);
        x_bf[(size_t)w * F + t]      = f2b((v0 - mu) * r * load_in(ln1g, t, isbf) + load_in(ln1b, t, isbf));
        x_bf[(size_t)w * F + t + 64] = f2b((v1 - mu) * r * load_in(ln1g, t + 64, isbf) + load_in(ln1b, t + 64, isbf));
        return;
    }
    // ---- weight/bias conversion path ----
    {
        int i = (bid - nbDeg - nbLn) * 256 + threadIdx.x;
        int isbf = flag[0];
        if (i < 180224) {
            const void* srcp; int j;
            if (i < 16384)       { srcp = w_head; j = i; }
            else if (i < 32768)  { srcp = w_tail; j = i - 16384; }
            else if (i < 49152)  { srcp = w_ent;  j = i - 32768; }
            else if (i < 114688) { srcp = ff_w1;  j = i - 49152; }
            else                 { srcp = ff_w2;  j = i - 114688; }
            wblob[i] = f2b(load_in(srcp, j, isbf));
        } else if (i < 180992) {
            int k = i - 180224;
            const void* srcp; int j;
            if (k < 128)      { srcp = attn;  j = k; }
            else if (k < 640) { srcp = ff_b1; j = k - 128; }
            else              { srcp = ff_b2; j = k - 640; }
            fblob[k] = load_in(srcp, j, isbf);
        }
    }
}

__global__ void scan1_k(const int* __restrict__ in8, int* partial, int* blk_sum, int N) {
    __shared__ int sh[256];
    int t = threadIdx.x;
    int i = blockIdx.x * 256 + t;
    int c = 0;
    if (i < N) {
#pragma unroll
        for (int s = 0; s < 8; ++s) c += in8[s * N + i];
    }
    sh[t] = c;
    __syncthreads();
    for (int o = 1; o < 256; o <<= 1) {
        int v = (t >= o) ? sh[t - o] : 0;
        __syncthreads();
        sh[t] += v;
        __syncthreads();
    }
    if (i < N) partial[i] = sh[t] - c;
    if (t == 255) blk_sum[blockIdx.x] = sh[255];
}

// fallback (nb > 256)
__global__ void scan2_k(const int* __restrict__ blk_sum, int* blk_off, int nb,
                        int* row_ptr, int N) {
    __shared__ int sh[256];
    int t = threadIdx.x;
    if (nb <= 256) {
        int v = (t < nb) ? blk_sum[t] : 0;
        sh[t] = v;
        __syncthreads();
        for (int o = 1; o < 256; o <<= 1) {
            int u = (t >= o) ? sh[t - o] : 0;
            __syncthreads();
            sh[t] += u;
            __syncthreads();
        }
        if (t < nb) blk_off[t] = sh[t] - v;
        if (t == 255) row_ptr[N] = sh[255];
    } else if (t == 0) {
        int run = 0;
        for (int b = 0; b < nb; ++b) { blk_off[b] = run; run += blk_sum[b]; }
        row_ptr[N] = run;
    }
}

__global__ void scan3_norms_k(const int* __restrict__ partial, const int* __restrict__ blk_off,
                              const int* __restrict__ in8, const int* __restrict__ out1,
                              int* row_ptr, int* soff, float* head_norm, float* tail_norm,
                              float* log_in, int N) {
    int i = blockIdx.x * 256 + threadIdx.x;
    if (i >= N) return;
    row_ptr[i] = partial[i] + blk_off[blockIdx.x];
    int run = 0;
#pragma unroll
    for (int s = 0; s < 8; ++s) { soff[s * N + i] = run; run += in8[s * N + i]; }
    int od = out1[i];
    float id = fmaxf((float)run, 1.0f);
    float odf = fmaxf((float)od, 1.0f);
    head_norm[i] = rsqrtf(odf);
    tail_norm[i] = sqrtf(id);
    log_in[i] = log1pf(id);
}

// fused scan2+scan3: each block re-scans blk_sum locally (nb <= 256)
__global__ void scan3f_k(const int* __restrict__ partial, const int* __restrict__ blk_sum,
                         int nb, const int* __restrict__ in8, const int* __restrict__ out1,
                         int* row_ptr, int* soff, float* head_norm, float* tail_norm,
                         float* log_in, int N) {
    __shared__ int bs[256];
    int t = threadIdx.x;
    bs[t] = (t < nb) ? blk_sum[t] : 0;
    __syncthreads();
    for (int o = 1; o < 256; o <<= 1) {
        int v = (t >= o) ? bs[t - o] : 0;
        __syncthreads();
        bs[t] += v;
        __syncthreads();
    }
    if (blockIdx.x == 0 && t == 0) row_ptr[N] = bs[nb - 1];
    int boff = (blockIdx.x == 0) ? 0 : bs[blockIdx.x - 1];
    int i = blockIdx.x * 256 + t;
    if (i >= N) return;
    row_ptr[i] = partial[i] + boff;
    int run = 0;
#pragma unroll
    for (int s = 0; s < 8; ++s) { soff[s * N + i] = run; run += in8[s * N + i]; }
    int od = out1[i];
    float id = fmaxf((float)run, 1.0f);
    float odf = fmaxf((float)od, 1.0f);
    head_norm[i] = rsqrtf(odf);
    tail_norm[i] = sqrtf(id);
    log_in[i] = log1pf(id);
}

// ---------------- FUSED mid-stage: atomic-free scatter (blocks first) + proj GEMM ----------------
__global__ void fused_mid_k(const int* __restrict__ src, const int* __restrict__ dst,
                            const int* __restrict__ row_ptr, const int* __restrict__ soff,
                            const uint32* __restrict__ pack, int* __restrict__ csr_src,
                            int E, int N, int nbSc, int Mb,
                            const __hip_bfloat16* __restrict__ X,
                            const __hip_bfloat16* __restrict__ Wall,
                            const float* __restrict__ head_norm,
                            __hip_bfloat16* __restrict__ fh,
                            __hip_bfloat16* __restrict__ ft,
                            uint32* __restrict__ fe_bf) {
    __shared__ __align__(16) char smem[2 * 64 * W1_STRIDE * 2];
    int bid = blockIdx.x;
    if (bid < nbSc) {
        // ---- scatter path: 8 edges/thread ----
        int base = bid * 2048 + threadIdx.x;
#pragma unroll
        for (int k = 0; k < 8; ++k) {
            int i = base + k * 256;
            if (i < E) {
                int d = dst[i];
                uint32 pk = pack[i];
                int s = (int)(pk >> 24);
                int r = (int)(pk & 0xFFFFFFu);
                csr_src[row_ptr[d] + soff[s * N + d] + r] = src[i];
            }
        }
        return;
    }
    // ---- projection GEMM path ----
    int pb = bid - nbSc;
    int g = pb / Mb;
    int bm = (pb - g * Mb) * 64;
    __hip_bfloat16* lx = (__hip_bfloat16*)smem;
    __hip_bfloat16* lw = (__hip_bfloat16*)(smem + 64 * W1_STRIDE * 2);
    float* eps = (float*)smem;
    int tid = threadIdx.x;
    int wv = tid >> 6, lane = tid & 63;
    int lr = lane & 15, quad = lane >> 4;
    int wsel = g >> 1;
    int wcb = (g & 1) * 64;
    {
        const __hip_bfloat16* xs = X + (size_t)bm * F;
        size_t maxe = (size_t)N * F;
#pragma unroll
        for (int i = 0; i < 4; ++i) {
            int idx = i * 2048 + tid * 8;
            int n = idx >> 7, k = idx & 127;
            size_t gi = (size_t)bm * F + idx;
            uint4 v = (gi + 8 <= maxe) ? *(const uint4*)(xs + idx)
                                       : *(const uint4*)(X + maxe - 8);
            *(uint4*)&lx[n * W1_STRIDE + k] = v;
        }
        const __hip_bfloat16* ws = Wall + ((size_t)wsel * F + wcb) * F;
#pragma unroll
        for (int i = 0; i < 4; ++i) {
            int idx = i * 2048 + tid * 8;
            int n = idx >> 7, k = idx & 127;
            *(uint4*)&lw[n * W1_STRIDE + k] = *(const uint4*)(ws + idx);
        }
    }
    __syncthreads();
    f32x4 acc[4] = {{0,0,0,0},{0,0,0,0},{0,0,0,0},{0,0,0,0}};
#pragma unroll
    for (int ks = 0; ks < 4; ++ks) {
        bf16x8 a = *reinterpret_cast<const bf16x8*>(&lx[(wv * 16 + lr) * W1_STRIDE + ks * 32 + quad * 8]);
#pragma unroll
        for (int j = 0; j < 4; ++j) {
            bf16x8 bb = *reinterpret_cast<const bf16x8*>(&lw[(j * 16 + lr) * W1_STRIDE + ks * 32 + quad * 8]);
            acc[j] = __builtin_amdgcn_mfma_f32_16x16x32_bf16(a, bb, acc[j], 0, 0, 0);
        }
    }
    __syncthreads();
    int rl = wv * 16 + quad * 4;
#pragma unroll
    for (int j = 0; j < 4; ++j)
#pragma unroll
        for (int r = 0; r < 4; ++r)
            eps[(rl + r) * LDS_STRIDE + j * 16 + lr] = acc[j][r];
    __syncthreads();
    int tr = tid >> 4, tc = (tid & 15) * 4;
#pragma unroll
    for (int p = 0; p < 4; ++p) {
        int row_l = p * 16 + tr;
        int grow = bm + row_l;
        if (grow >= N) continue;
        float4 v = *(const float4*)&eps[row_l * LDS_STRIDE + tc];
        float hn = head_norm[grow];
        v.x *= hn; v.y *= hn; v.z *= hn; v.w *= hn;
        size_t idx = (size_t)grow * F + wcb + tc;
        uint2 u; u.x = packbf2(v.x, v.y); u.y = packbf2(v.z, v.w);
        __hip_bfloat16* dstp = (wsel == 0) ? fh : (wsel == 1) ? ft : (__hip_bfloat16*)fe_bf;
        *(uint2*)&dstp[idx] = u;
    }
}

// ---------------- FUSED edge attention + softmax + hop0 (two-pass, proven R7) ----------------
// pass1: logits (16 lanes/edge), per-head max. pass2: lane t owns (edge t&7,
// head t>>3) -> ONE exp per lane (64 unique (edge,head) per batch), coalesced
// e_h load/store, __shfl distributes ex to the fe-gather accumulation.
__global__ void attn_hop0_k(const int* __restrict__ csr_src, const int* __restrict__ row_ptr,
                            const uint32* __restrict__ fh2, const uint32* __restrict__ ft2,
                            const float* __restrict__ attn_f, const float* __restrict__ log_in,
                            const float* __restrict__ tail_norm, const float* __restrict__ head_norm,
                            const uint32* __restrict__ fe_bf,
                            __half* __restrict__ e_h, float* __restrict__ inv_arr,
                            uint32* __restrict__ out_bf, int N) {
    int w = blockIdx.x * (blockDim.x >> 6) + (threadIdx.x >> 6);
    if (w >= N) return;
    int t = threadIdx.x & 63;
    int g = t >> 4, j = t & 15;
    int b = row_ptr[w], e = row_ptr[w + 1];
    // ---- pass1: logits ----
    uint4 fr = ((const uint4*)ft2)[(size_t)w * 16 + j];
    float ftf[8] = {bflo(fr.x), bfhi(fr.x), bflo(fr.y), bfhi(fr.y),
                    bflo(fr.z), bfhi(fr.z), bflo(fr.w), bfhi(fr.w)};
    float c1[8], c2[8];
#pragma unroll
    for (int k = 0; k < 8; ++k) {
        float at = attn_f[8 * j + k];
        c1[k] = 0.6f * at * ftf[k];
        c2[k] = 0.4f * at * fabsf(ftf[k]);
    }
    float scale = log_in[w] * (1.0f / 16.0f);
    float m = -1e30f;
    for (int p0 = b; p0 < e; p0 += 8) {
        int pa = p0 + g, pb = p0 + 4 + g;
        bool oka = pa < e, okb = pb < e;
        int sa = csr_src[oka ? pa : b];
        int sb = csr_src[okb ? pb : b];
        uint4 ga = ((const uint4*)fh2)[(size_t)sa * 16 + j];
        uint4 gb = ((const uint4*)fh2)[(size_t)sb * 16 + j];
        float ra = edge_dot2(ga, c1, c2);
        float rb = edge_dot2(gb, c1, c2);
        ra += __shfl_xor(ra, 1, 64);
        rb += __shfl_xor(rb, 1, 64);
        float la = ra * scale, lb = rb * scale;
        if (oka) { if (!(j & 1)) e_h[(size_t)pa * 8 + (j >> 1)] = __float2half(la); m = fmaxf(m, la); }
        if (okb) { if (!(j & 1)) e_h[(size_t)pb * 8 + (j >> 1)] = __float2half(lb); m = fmaxf(m, lb); }
    }
    m = fmaxf(m, __shfl_xor(m, 16, 64));
    m = fmaxf(m, __shfl_xor(m, 32, 64));
    // ---- pass2: lane t owns (edge t&7, head t>>3); one exp/lane/batch ----
    int h = t >> 3;
    int il = t & 7;
    float mh = __shfl(m, h * 2, 64);
    float sum = 0.f, a0 = 0.f, a1 = 0.f;
    for (int p = b; p < e; p += 8) {
        int qo = p + il;
        bool okm = qo < e;
        int qm = okm ? qo : b;
        float lg = __half2float(e_h[(size_t)qm * 8 + h]);
        float exm = okm ? __expf(lg - mh) : 0.f;
        if (okm) e_h[(size_t)qm * 8 + h] = __float2half(exm);
        int srcs[8];
#pragma unroll
        for (int i = 0; i < 8; ++i) {
            int qi = p + i;
            srcs[i] = csr_src[qi < e ? qi : b];
        }
        uint32 rows[8];
#pragma unroll
        for (int i = 0; i < 8; ++i) rows[i] = fe_bf[(size_t)srcs[i] * 64 + t];
#pragma unroll
        for (int i = 0; i < 8; ++i) {
            float exi = __shfl(exm, (t & 56) | i, 64);
            sum += exi;
            a0 = fmaf(bflo(rows[i]), exi, a0);
            a1 = fmaf(bfhi(rows[i]), exi, a1);
        }
    }
    float inv = 1.0f / fmaxf(sum, 1e-30f);
    if ((t & 7) == 0) inv_arr[(size_t)w * 8 + h] = inv;
    float tl = tail_norm[w] * 0.9f * inv;
    uint32 fe_l = fe_bf[(size_t)w * 64 + t];
    float r0 = tl * a0 + 0.1f * bflo(fe_l);
    float r1 = tl * a1 + 0.1f * bfhi(fe_l);
    float hn = head_norm[w];
    out_bf[(size_t)w * 64 + t] = packbf2(r0 * hn, r1 * hn);
}

// ---------------- diffusion hop: 2 nodes/wave (half-wave each), batch-8 edges ----------------
// last hop fuses LN2: half-wave holds full 128-feat row -> shuffle-reduce stats,
// writes both rst (f32, FFN residual) and y_bf (normalized bf16, FFN input).
__global__ void hop_k(const uint32* __restrict__ gsrc2, const __half* __restrict__ e_h,
                      const float* __restrict__ inv_arr,
                      const int* __restrict__ csr_src, const int* __restrict__ row_ptr,
                      const float* __restrict__ tail_norm, const float* __restrict__ head_norm,
                      const uint32* __restrict__ fe_bf, const void* __restrict__ feat,
                      const void* __restrict__ ln2g, const void* __restrict__ ln2b,
                      const int* __restrict__ flag,
                      uint32* __restrict__ out_bf, float* __restrict__ out_f32,
                      int last, int N) {
    int w = blockIdx.x * 8 + (threadIdx.x >> 5);   // 8 half-waves per 256-thr block
    if (w >= N) return;
    int l = threadIdx.x & 31;                      // features [4l, 4l+4)
    int h = l >> 2;
    int b = row_ptr[w], e = row_ptr[w + 1];
    float inv = inv_arr[(size_t)w * 8 + h];
    float a0 = 0.f, a1 = 0.f, a2 = 0.f, a3 = 0.f;
    int p = b;
    for (; p + 8 <= e; p += 8) {
        int s[8]; float av[8]; uint2 gg[8];
#pragma unroll
        for (int i = 0; i < 8; ++i) s[i] = csr_src[p + i];
#pragma unroll
        for (int i = 0; i < 8; ++i) av[i] = __half2float(e_h[(size_t)(p + i) * 8 + h]);
#pragma unroll
        for (int i = 0; i < 8; ++i) gg[i] = ((const uint2*)gsrc2)[(size_t)s[i] * 32 + l];
#pragma unroll
        for (int i = 0; i < 8; ++i) {
            a0 += bflo(gg[i].x) * av[i]; a1 += bfhi(gg[i].x) * av[i];
            a2 += bflo(gg[i].y) * av[i]; a3 += bfhi(gg[i].y) * av[i];
        }
    }
    if (p < e) {
        int s[8]; float av[8]; uint2 gg[8];
#pragma unroll
        for (int i = 0; i < 8; ++i) {
            int q = p + i;
            bool ok = q < e;
            int q2 = ok ? q : b;
            s[i] = csr_src[q2];
            av[i] = ok ? __half2float(e_h[(size_t)q * 8 + h]) : 0.f;
        }
#pragma unroll
        for (int i = 0; i < 8; ++i) gg[i] = ((const uint2*)gsrc2)[(size_t)s[i] * 32 + l];
#pragma unroll
        for (int i = 0; i < 8; ++i) {
            a0 += bflo(gg[i].x) * av[i]; a1 += bfhi(gg[i].x) * av[i];
            a2 += bflo(gg[i].y) * av[i]; a3 += bfhi(gg[i].y) * av[i];
        }
    }
    float tl = tail_norm[w] * 0.9f * inv;
    uint2 feu = ((const uint2*)fe_bf)[(size_t)w * 32 + l];
    float r0 = tl * a0 + 0.1f * bflo(feu.x);
    float r1 = tl * a1 + 0.1f * bfhi(feu.x);
    float r2 = tl * a2 + 0.1f * bflo(feu.y);
    float r3 = tl * a3 + 0.1f * bfhi(feu.y);
    if (last) {
        int isbf = flag[0];
        float4 o;
        if (isbf) {
            uint2 fu = ((const uint2*)feat)[(size_t)w * 32 + l];
            o.x = r0 + bflo(fu.x); o.y = r1 + bfhi(fu.x);
            o.z = r2 + bflo(fu.y); o.w = r3 + bfhi(fu.y);
        } else {
            float4 fv = ((const float4*)feat)[(size_t)w * 32 + l];
            o.x = r0 + fv.x; o.y = r1 + fv.y; o.z = r2 + fv.z; o.w = r3 + fv.w;
        }
        ((float4*)out_f32)[(size_t)w * 32 + l] = o;
        // fused LN2 over the 32-lane half-wave (128 features)
        float s2 = o.x + o.y + o.z + o.w;
        float sq = o.x * o.x + o.y * o.y + o.z * o.z + o.w * o.w;
#pragma unroll
        for (int mm = 1; mm < 32; mm <<= 1) {
            s2 += __shfl_xor(s2, mm, 64);
            sq += __shfl_xor(sq, mm, 64);
        }
        float mu = s2 * (1.0f / F);
        float var = fmaxf(sq * (1.0f / F) - mu * mu, 0.0f);
        float rr = rsqrtf(var + 1e-5f);
        float g0 = load_in(ln2g, 4 * l + 0, isbf), g1 = load_in(ln2g, 4 * l + 1, isbf);
        float g2 = load_in(ln2g, 4 * l + 2, isbf), g3 = load_in(ln2g, 4 * l + 3, isbf);
        float b0 = load_in(ln2b, 4 * l + 0, isbf), b1 = load_in(ln2b, 4 * l + 1, isbf);
        float b2 = load_in(ln2b, 4 * l + 2, isbf), b3 = load_in(ln2b, 4 * l + 3, isbf);
        uint2 u;
        u.x = packbf2((o.x - mu) * rr * g0 + b0, (o.y - mu) * rr * g1 + b1);
        u.y = packbf2((o.z - mu) * rr * g2 + b2, (o.w - mu) * rr * g3 + b3);
        ((uint2*)out_bf)[(size_t)w * 32 + l] = u;
    } else {
        float hn = head_norm[w];
        uint2 u;
        u.x = packbf2(r0 * hn, r1 * hn);
        u.y = packbf2(r2 * hn, r3 * hn);
        ((uint2*)out_bf)[(size_t)w * 32 + l] = u;
    }
}

// ---------------- FUSED FFN v3 (LDS-staged weights) ----------------
__global__ __launch_bounds__(256, 2)
void ffn_fused_k(const __hip_bfloat16* __restrict__ Y, const __hip_bfloat16* __restrict__ W1,
                 const __hip_bfloat16* __restrict__ W2, const float* __restrict__ b1f,
                 const float* __restrict__ b2f, const float* __restrict__ rst,
                 const int* __restrict__ flag, void* __restrict__ out, int N) {
    __shared__ __align__(16) char smem[45056];
    __hip_bfloat16* lw1 = (__hip_bfloat16*)smem;
    __hip_bfloat16* lw2 = (__hip_bfloat16*)(smem + 17408);
    __hip_bfloat16* tb  = (__hip_bfloat16*)(smem + 35840);
    float* eps = (float*)smem;
    int tid = threadIdx.x;
    int wv = tid >> 6, lane = tid & 63;
    int lr = lane & 15, quad = lane >> 4;
    int bm = blockIdx.x * 64;
    int row_a = bm + wv * 16 + lr;
    if (row_a >= N) row_a = N - 1;
    bf16x8 ay[4];
    {
        const __hip_bfloat16* yr = Y + (size_t)row_a * F + quad * 8;
#pragma unroll
        for (int ks = 0; ks < 4; ++ks) ay[ks] = *reinterpret_cast<const bf16x8*>(yr + ks * 32);
    }
    f32x4 o[8];
#pragma unroll
    for (int j = 0; j < 8; ++j) o[j] = (f32x4){0,0,0,0};
    __hip_bfloat16* tbuf = tb + wv * (16 * TB_STRIDE);
    for (int c = 0; c < 8; ++c) {
        int nb0 = c * 64;
        __syncthreads();
        {
            const __hip_bfloat16* s1 = W1 + (size_t)nb0 * F;
#pragma unroll
            for (int i = 0; i < 4; ++i) {
                int idx = i * 2048 + tid * 8;
                int n = idx >> 7, k = idx & 127;
                *(uint4*)&lw1[n * W1_STRIDE + k] = *(const uint4*)(s1 + idx);
            }
#pragma unroll
            for (int i = 0; i < 4; ++i) {
                int idx = i * 2048 + tid * 8;
                int r = idx >> 6, k2 = idx & 63;
                *(uint4*)&lw2[r * W2_STRIDE + k2] = *(const uint4*)(W2 + (size_t)r * 512 + nb0 + k2);
            }
        }
        __syncthreads();
        f32x4 t[4] = {{0,0,0,0},{0,0,0,0},{0,0,0,0},{0,0,0,0}};
#pragma unroll
        for (int ks = 0; ks < 4; ++ks) {
#pragma unroll
            for (int j = 0; j < 4; ++j) {
                bf16x8 bb = *reinterpret_cast<const bf16x8*>(&lw1[(j * 16 + lr) * W1_STRIDE + ks * 32 + quad * 8]);
                t[j] = __builtin_amdgcn_mfma_f32_16x16x32_bf16(ay[ks], bb, t[j], 0, 0, 0);
            }
        }
#pragma unroll
        for (int j = 0; j < 4; ++j) {
            float bias = b1f[nb0 + 16 * j + lr];
#pragma unroll
            for (int r = 0; r < 4; ++r) {
                float v = fmaxf(t[j][r] + bias, 0.f);
                tbuf[(quad * 4 + r) * TB_STRIDE + j * 16 + lr] = f2b(v);
            }
        }
#pragma unroll
        for (int ks2 = 0; ks2 < 2; ++ks2) {
            bf16x8 at = *reinterpret_cast<const bf16x8*>(&tbuf[lr * TB_STRIDE + ks2 * 32 + quad * 8]);
#pragma unroll
            for (int j2 = 0; j2 < 8; ++j2) {
                bf16x8 bb = *reinterpret_cast<const bf16x8*>(&lw2[(j2 * 16 + lr) * W2_STRIDE + ks2 * 32 + quad * 8]);
                o[j2] = __builtin_amdgcn_mfma_f32_16x16x32_bf16(at, bb, o[j2], 0, 0, 0);
            }
        }
    }
    __syncthreads();
    int rl = wv * 16 + quad * 4;
#pragma unroll
    for (int j = 0; j < 8; ++j)
#pragma unroll
        for (int r = 0; r < 4; ++r)
            eps[(rl + r) * 132 + j * 16 + lr] = o[j][r];
    __syncthreads();
    int isbf = flag[0];
#pragma unroll
    for (int p = 0; p < 8; ++p) {
        int idx = p * 1024 + tid * 4;
        int row_l = idx >> 7, col = idx & 127;
        int grow = bm + row_l;
        if (grow >= N) continue;
        float4 v = *(const float4*)&eps[row_l * 132 + col];
        float4 bias = *(const float4*)&b2f[col];
        float4 rv = *(const float4*)&rst[(size_t)grow * F + col];
        v.x += bias.x + rv.x; v.y += bias.y + rv.y;
        v.z += bias.z + rv.z; v.w += bias.w + rv.w;
        size_t gidx = (size_t)grow * F + col;
        if (isbf) {
            uint2 u; u.x = packbf2(v.x, v.y); u.y = packbf2(v.z, v.w);
            *(uint2*)&((__hip_bfloat16*)out)[gidx] = u;
        } else {
            *(float4*)&((float*)out)[gidx] = v;
        }
    }
}

extern "C" void kernel_launch(void* const* d_in, const int* in_sizes, int n_in,
                              void* d_out, int out_size, void* d_ws, size_t ws_size,
                              hipStream_t stream) {
    if (n_in < 15) return;
    const void* feat = d_in[0];
    const int* src = (const int*)d_in[1];
    const int* dst = (const int*)d_in[2];
    const void* w_head = d_in[3];
    const void* w_tail = d_in[4];
    const void* w_ent  = d_in[5];
    const void* attn   = d_in[6];
    const void* ln1_g  = d_in[7];
    const void* ln1_b  = d_in[8];
    const void* ln2_g  = d_in[9];
    const void* ln2_b  = d_in[10];
    const void* ff_w1  = d_in[11];
    const void* ff_b1  = d_in[12];
    const void* ff_w2  = d_in[13];
    const void* ff_b2  = d_in[14];

    const int N = in_sizes[0] / F;
    const int E = in_sizes[1];
    (void)out_size;

    char* base = (char*)d_ws;
    size_t off = 0;
    auto alloc = [&](size_t bytes) -> void* {
        void* r = base + off;
        off += (bytes + 255) & ~(size_t)255;
        return r;
    };
    int* zr        = (int*)alloc((size_t)9 * N * 4);   // in8 | out1 (zeroed)
    int* in8 = zr, * out1 = zr + 8 * N;
    int* soff      = (int*)alloc((size_t)8 * N * 4);
    int* row_ptr   = (int*)alloc((size_t)(N + 1) * 4);
    int* partial   = (int*)alloc((size_t)N * 4);
    int* blk_sum   = (int*)alloc((size_t)1024 * 4);
    int* blk_off   = (int*)alloc((size_t)1024 * 4);
    int* flag      = (int*)alloc(256);
    float* head_norm = (float*)alloc((size_t)N * 4);
    float* tail_norm = (float*)alloc((size_t)N * 4);
    float* log_in    = (float*)alloc((size_t)N * 4);
    float* inv_arr   = (float*)alloc((size_t)N * 8 * 4);
    int* csr_src   = (int*)alloc((size_t)E * 4);
    uint32* pack   = (uint32*)alloc((size_t)E * 4);
    __hip_bfloat16* wh_bf = (__hip_bfloat16*)alloc((size_t)F * F * 2);   // blob start
    __hip_bfloat16* wt_bf = (__hip_bfloat16*)alloc((size_t)F * F * 2);
    __hip_bfloat16* we_bf = (__hip_bfloat16*)alloc((size_t)F * F * 2);
    __hip_bfloat16* w1_bf = (__hip_bfloat16*)alloc((size_t)512 * F * 2);
    __hip_bfloat16* w2_bf = (__hip_bfloat16*)alloc((size_t)F * 512 * 2);
    float* attn_f    = (float*)alloc((size_t)F * 4);
    float* b1f       = (float*)alloc((size_t)512 * 4);
    float* b2f_      = (float*)alloc((size_t)F * 4);
    __hip_bfloat16* x_bf = (__hip_bfloat16*)alloc((size_t)N * F * 2);
    __hip_bfloat16* fh   = (__hip_bfloat16*)alloc((size_t)N * F * 2);
    __hip_bfloat16* ftb  = (__hip_bfloat16*)alloc((size_t)N * F * 2);
    uint32* fe_bf = (uint32*)alloc((size_t)N * F * 2);
    uint32* hA_bf = (uint32*)alloc((size_t)N * F * 2);
    uint32* hB_bf = (uint32*)alloc((size_t)N * F * 2);
    float* rst = (float*)alloc((size_t)N * F * 4);
    __hip_bfloat16* y_bf = (__hip_bfloat16*)hA_bf;
    __half* e_h = (__half*)x_bf;   // x_bf is dead after fused_mid (proj); E*8*2 <= N*F*2
    (void)wt_bf; (void)we_bf;
    if (off > ws_size) return;

    const int Mb = (N + 63) / 64;
    const int nodeBlocks = (N + 3) / 4;
    const int hopBlocks = (N + 7) / 8;
    const int nb = (N + 255) / 256;
    const int nbDeg = (E + 2047) / 2048;
    const int nbLn  = (N + 3) / 4;
    const int nbCvt = (180992 + 255) / 256;

    detect_k<<<1, 256, 0, stream>>>((const uint32*)feat, flag);
    hipMemsetAsync(zr, 0, (size_t)9 * N * 4, stream);

    fused_pre_k<<<nbDeg + nbLn + nbCvt, 256, 0, stream>>>(
        src, dst, in8, out1, pack, E,
        feat, ln1_g, ln1_b,
        w_head, w_tail, w_ent, ff_w1, ff_w2, attn, ff_b1, ff_b2,
        flag, wh_bf, attn_f, x_bf, nbDeg, nbLn, N);

    scan1_k<<<nb, 256, 0, stream>>>(in8, partial, blk_sum, N);
    if (nb <= 256) {
        scan3f_k<<<nb, 256, 0, stream>>>(partial, blk_sum, nb, in8, out1,
                                         row_ptr, soff, head_norm, tail_norm, log_in, N);
    } else {
        scan2_k<<<1, 256, 0, stream>>>(blk_sum, blk_off, nb, row_ptr, N);
        scan3_norms_k<<<nb, 256, 0, stream>>>(partial, blk_off, in8, out1,
                                              row_ptr, soff, head_norm, tail_norm, log_in, N);
    }

    const int nbSc = (E + 2047) / 2048;
    fused_mid_k<<<nbSc + Mb * 6, 256, 0, stream>>>(
        src, dst, row_ptr, soff, pack, csr_src, E, N, nbSc, Mb,
        x_bf, wh_bf, head_norm, fh, ftb, fe_bf);

    // fused attention softmax + hop0 (writes hA_bf)
    attn_hop0_k<<<nodeBlocks, 256, 0, stream>>>(csr_src, row_ptr, (const uint32*)fh,
                                                (const uint32*)ftb, attn_f, log_in,
                                                tail_norm, head_norm, fe_bf,
                                                e_h, inv_arr, hA_bf, N);

    const uint32* gsrc = hA_bf;
    uint32* bufs[2] = {hA_bf, hB_bf};
    for (int hop = 1; hop < HOPS; ++hop) {
        int last = (hop == HOPS - 1);
        uint32* dst_bf = last ? (uint32*)y_bf : bufs[hop & 1];
        hop_k<<<hopBlocks, 256, 0, stream>>>(gsrc, e_h, inv_arr, csr_src, row_ptr, tail_norm,
                                             head_norm, fe_bf, feat, ln2_g, ln2_b, flag,
                                             dst_bf, rst, last, N);
        if (!last) gsrc = dst_bf;
    }

    ffn_fused_k<<<Mb, 256, 0, stream>>>(y_bf, w1_bf, w2_bf, b1f, b2f_, rst, flag, d_out, N);
}